// Round 5
// baseline (3179.396 us; speedup 1.0000x reference)
//
#include <hip/hip_runtime.h>
#include <math.h>

// ---- problem constants ----
#define BATCH   16
#define SEQ     96
#define NVARS   862
#define NMARK   4
#define LTOK    866          // NVARS + NMARK
#define MROWS   (BATCH*LTOK) // 13856
#define DM      512
#define DSTATE  16
#define DTRANK  32
#define DFF     512
#define PRED    96
#define EPS_F   1e-5f

// chunked parallel scan
#define CCH     32           // chunks per sequence
#define TCH     28           // steps per chunk (32*28=896 >= 866)

typedef __attribute__((ext_vector_type(4))) float f32x4;
typedef __attribute__((ext_vector_type(8))) short bf16x8;  // 8 bf16 in 4 VGPRs
typedef unsigned short ushort_t;

__device__ __forceinline__ short f2bf(float f) {
    unsigned u = __builtin_bit_cast(unsigned, f);
    u += 0x7fffu + ((u >> 16) & 1u);          // round-to-nearest-even
    return (short)(u >> 16);
}
__device__ __forceinline__ float bf2f(ushort_t u) {
    return __builtin_bit_cast(float, (unsigned)u << 16);
}

// direct global->LDS 16B async copy. LDS dest = wave-uniform base + lane*16.
__device__ __forceinline__ void gl2lds16(const ushort_t* g, ushort_t* l) {
    __builtin_amdgcn_global_load_lds(
        (const __attribute__((address_space(1))) unsigned int*)(g),
        (__attribute__((address_space(3))) unsigned int*)(l),
        16, 0, 0);
}

// =====================================================================
// bf16 GEMM (m97 structure): out = act(A . W^T + bias) + res
// A bf16 row-major (lda), W bf16 row-major (N x ldw). Tile 128x128, BK=32,
// 256 thr = 4 waves (2x2), each wave 64x64 via 4x4 frags of 16x16x32.
// Staging via global_load_lds with LINEAR LDS + XOR-swizzled global source
// (k-group g = c ^ ((row>>1)&3)) so ds_read_b128 frag reads are 2-way max.
// rev: A rows reversed within each LTOK segment (clamped at edges).
// mode: 0 = normal (outf fp32 and/or outb bf16, stride ldo)
//       1 = final: denormed transposed write into d_out (B, PRED, NVARS)
//       2 = split xz: cols<512 -> outf (xi fp32), cols>=512 -> outb (z bf16)
// K multiple of 32. Row starts must be 16B aligned (lda even*).
// =====================================================================
__global__ __launch_bounds__(256) void gemm_bf16(
    const ushort_t* __restrict__ A, int lda,
    const ushort_t* __restrict__ W, int ldw,
    const float* __restrict__ bias,
    const float* __restrict__ resf, const ushort_t* __restrict__ resb,
    float* __restrict__ outf, ushort_t* __restrict__ outb, int ldo,
    int M, int N, int K, int rev, int act, int mode,
    const float* __restrict__ fstd, const float* __restrict__ fmean)
{
    __shared__ ushort_t Als[128 * 32];
    __shared__ ushort_t Bls[128 * 32];
    const int tid  = threadIdx.x;
    const int lane = tid & 63;
    const int w    = tid >> 6;
    const int wm   = w >> 1;          // wave row (0..1)
    const int wn   = w & 1;           // wave col (0..1)
    const int m0 = blockIdx.y * 128, n0 = blockIdx.x * 128;

    // per-lane global source offsets for the 2 load_lds issues (A and B each)
    size_t asrc[2], wsrc[2];
    int lbase[2];                     // wave-uniform LDS base (shorts)
#pragma unroll
    for (int i = 0; i < 2; ++i) {
        const int byte = (i * 4 + w) * 1024 + lane * 16;  // this lane's LDS slot
        const int row  = byte >> 6;                        // 0..127
        const int c    = (byte >> 4) & 3;
        const int g    = c ^ ((row >> 1) & 3);             // swizzled k-group
        int gm = m0 + row; if (gm > M - 1) gm = M - 1;
        int rm = gm;
        if (rev) { int b = gm / LTOK; int t = gm - b * LTOK; rm = b * LTOK + (LTOK - 1 - t); }
        asrc[i] = (size_t)rm * lda + g * 8;
        int gn = n0 + row; if (gn > N - 1) gn = N - 1;
        wsrc[i] = (size_t)gn * ldw + g * 8;
        lbase[i] = (i * 4 + w) * 512;                      // shorts
    }

    f32x4 acc[4][4];
#pragma unroll
    for (int i = 0; i < 4; ++i)
#pragma unroll
        for (int j = 0; j < 4; ++j) { f32x4 z = {0.f, 0.f, 0.f, 0.f}; acc[i][j] = z; }

    const int fr = lane & 15;         // frag row (A) / col (B)
    const int kg = lane >> 4;         // k-group 0..3
    const int cg = kg ^ ((fr >> 1) & 3);  // swizzled LDS column group

    for (int k0 = 0; k0 < K; k0 += 32) {
        __syncthreads();              // prior frag reads done before overwrite
        gl2lds16(A + asrc[0] + k0, &Als[lbase[0]]);
        gl2lds16(A + asrc[1] + k0, &Als[lbase[1]]);
        gl2lds16(W + wsrc[0] + k0, &Bls[lbase[0]]);
        gl2lds16(W + wsrc[1] + k0, &Bls[lbase[1]]);
        __syncthreads();              // drains vmcnt -> LDS valid

        bf16x8 a4[4], b4[4];
#pragma unroll
        for (int i = 0; i < 4; ++i) {
            a4[i] = *(const bf16x8*)&Als[(wm * 64 + i * 16 + fr) * 32 + cg * 8];
            b4[i] = *(const bf16x8*)&Bls[(wn * 64 + i * 16 + fr) * 32 + cg * 8];
        }
#pragma unroll
        for (int mi = 0; mi < 4; ++mi)
#pragma unroll
            for (int ni = 0; ni < 4; ++ni)
                acc[mi][ni] = __builtin_amdgcn_mfma_f32_16x16x32_bf16(
                    a4[mi], b4[ni], acc[mi][ni], 0, 0, 0);
    }

    // epilogue: C/D layout col=lane&15, row=(lane>>4)*4+j   [m89-verified]
#pragma unroll
    for (int mi = 0; mi < 4; ++mi) {
#pragma unroll
        for (int ni = 0; ni < 4; ++ni) {
            const int gn = n0 + wn * 64 + ni * 16 + fr;
            if (gn >= N) continue;
#pragma unroll
            for (int j = 0; j < 4; ++j) {
                const int gm = m0 + wm * 64 + mi * 16 + kg * 4 + j;
                if (gm >= M) continue;
                float v = acc[mi][ni][j];
                if (bias) v += bias[gn];
                if (act == 1) v = fmaxf(v, 0.f);
                else if (act == 2) v = (v > 20.f) ? v : log1pf(__expf(v)); // softplus
                if (resf) v += resf[(size_t)gm * DM + gn];
                else if (resb) v += bf2f(resb[(size_t)gm * DM + gn]);
                if (mode == 0) {
                    if (outf) outf[(size_t)gm * ldo + gn] = v;
                    if (outb) outb[(size_t)gm * ldo + gn] = (ushort_t)f2bf(v);
                } else if (mode == 2) {
                    if (gn < DM) outf[(size_t)gm * DM + gn] = v;
                    else         outb[(size_t)gm * DM + gn - DM] = (ushort_t)f2bf(v);
                } else {
                    const int bb = gm / LTOK, vv = gm - bb * LTOK;
                    if (vv < NVARS) {
                        outf[((size_t)bb * PRED + gn) * NVARS + vv] =
                            v * fstd[bb * NVARS + vv] + fmean[bb * NVARS + vv];
                    }
                }
            }
        }
    }
}

// ---- fp32 -> bf16 weight conversion, 12 jobs in one kernel ----
struct CvtJobs {
    const float* src[12];
    ushort_t*    dst[12];
    int          n[12];
};
__global__ void cvt_kernel(CvtJobs jobs) {
    const int j = blockIdx.y;
    const float* s = jobs.src[j];
    ushort_t* d = jobs.dst[j];
    const int n = jobs.n[j];
    for (int i = blockIdx.x * blockDim.x + threadIdx.x; i < n; i += gridDim.x * blockDim.x)
        d[i] = (ushort_t)f2bf(s[i]);
}

// ---- per-(b,var) mean / stdev over SEQ ----
__global__ void stats_kernel(const float* __restrict__ x_enc,
                             float* __restrict__ means, float* __restrict__ stdev)
{
    int i = blockIdx.x * blockDim.x + threadIdx.x;
    if (i >= BATCH * NVARS) return;
    int b = i / NVARS, v = i - b * NVARS;
    const float* p = x_enc + (size_t)b * SEQ * NVARS + v;
    float s = 0.f;
    for (int t = 0; t < SEQ; ++t) s += p[(size_t)t * NVARS];
    float mu = s / (float)SEQ;
    float ss = 0.f;
    for (int t = 0; t < SEQ; ++t) { float d = p[(size_t)t * NVARS] - mu; ss += d * d; }
    means[i] = mu;
    stdev[i] = sqrtf(ss / (float)SEQ + EPS_F);
}

// ---- build token matrix (MROWS x SEQ) in bf16 ----
__global__ void tok_kernel(const float* __restrict__ x_enc, const float* __restrict__ x_mark,
                           const float* __restrict__ means, const float* __restrict__ stdev,
                           ushort_t* __restrict__ tok)
{
    int i = blockIdx.x * blockDim.x + threadIdx.x;
    if (i >= MROWS * SEQ) return;
    int s = i % SEQ;
    int row = i / SEQ;
    int b = row / LTOK, l = row - b * LTOK;
    float val;
    if (l < NVARS) {
        val = (x_enc[((size_t)b * SEQ + s) * NVARS + l] - means[b * NVARS + l])
              / stdev[b * NVARS + l];
    } else {
        val = x_mark[((size_t)b * SEQ + s) * NMARK + (l - NVARS)];
    }
    tok[i] = (ushort_t)f2bf(val);
}

// ---- causal depthwise conv (width 2) + SiLU; xi (MROWS x 512) fp32 ----
__global__ void conv_silu_kernel(const float* __restrict__ xi, float* __restrict__ xc,
                                 ushort_t* __restrict__ xc_bf,
                                 const float* __restrict__ cW, const float* __restrict__ cb)
{
    int i = blockIdx.x * blockDim.x + threadIdx.x;
    if (i >= MROWS * DM) return;
    int d = i & (DM - 1);
    int row = i >> 9;
    int t = row % LTOK;
    float cur = xi[i];
    float prev = (t == 0) ? 0.f : xi[i - DM];
    float v = prev * cW[d * 2 + 0] + cur * cW[d * 2 + 1] + cb[d];
    float sv = v * (1.f / (1.f + __expf(-v)));   // silu
    xc[i] = sv;
    xc_bf[i] = (ushort_t)f2bf(sv);
}

// =====================================================================
// Chunked parallel selective scan (3 passes), one-lane-per-channel.
// =====================================================================
__global__ __launch_bounds__(256) void scan1_kernel(
    const float* __restrict__ xc, const float* __restrict__ dt,
    const float* __restrict__ dbc, const float* __restrict__ A_log,
    float* __restrict__ aprod, float* __restrict__ hpart)
{
    __shared__ float Ls[TCH * 32];
    const int tid = threadIdx.x;
    const int d = blockIdx.x * 256 + tid;
    const int c = blockIdx.y;
    const int b = blockIdx.z;
    const int t0 = c * TCH;
    const int tend = min(t0 + TCH, LTOK);
    const size_t rowb = (size_t)b * LTOK;

    for (int i = tid; i < TCH * 32; i += 256) {
        const int tr = min(t0 + (i >> 5), LTOK - 1);
        Ls[i] = dbc[(rowb + tr) * 64 + 32 + (i & 31)];
    }
    __syncthreads();

    float Ads[16];
#pragma unroll
    for (int s = 0; s < 16; ++s) Ads[s] = -__expf(A_log[d * DSTATE + s]);
    float h[16];
#pragma unroll
    for (int s = 0; s < 16; ++s) h[s] = 0.f;
    float sumdt = 0.f;

    for (int t = t0; t < tend; ++t) {
        const size_t row = rowb + t;
        const float dtv = dt[row * DM + d];
        const float xcv = xc[row * DM + d];
        const float du = dtv * xcv;
        sumdt += dtv;
        const float* Bp = &Ls[(t - t0) * 32];
#pragma unroll
        for (int s = 0; s < 16; ++s) {
            const float dA = __expf(dtv * Ads[s]);
            h[s] = dA * h[s] + du * Bp[s];
        }
    }
#pragma unroll
    for (int s = 0; s < 16; ++s) {
        const size_t oidx = ((size_t)(b * CCH + c) * 16 + s) * DM + d;
        aprod[oidx] = __expf(Ads[s] * sumdt);
        hpart[oidx] = h[s];
    }
}

// scan2: sequential combine over chunks; writes hinit IN-PLACE into aprod.
__global__ __launch_bounds__(256) void scan2_kernel(
    float* __restrict__ aprod, const float* __restrict__ hpart)
{
    const int gid = blockIdx.x * 256 + threadIdx.x;   // BATCH*16*DM = 131072
    const int d = gid & (DM - 1);
    const int s = (gid >> 9) & 15;
    const int b = gid >> 13;
    float h = 0.f;
    for (int c = 0; c < CCH; ++c) {
        const size_t idx = ((size_t)(b * CCH + c) * 16 + s) * DM + d;
        const float ap = aprod[idx];
        const float hp = hpart[idx];
        aprod[idx] = h;               // hinit
        h = hp + ap * h;
    }
}

__global__ __launch_bounds__(256) void scan3_kernel(
    const float* __restrict__ xc, const float* __restrict__ dt,
    const float* __restrict__ dbc, const ushort_t* __restrict__ zbf,
    const float* __restrict__ A_log, const float* __restrict__ Dp,
    const float* __restrict__ hinit, ushort_t* __restrict__ ym)
{
    __shared__ float Ls[TCH * 32];
    const int tid = threadIdx.x;
    const int d = blockIdx.x * 256 + tid;
    const int c = blockIdx.y;
    const int b = blockIdx.z;
    const int t0 = c * TCH;
    const int tend = min(t0 + TCH, LTOK);
    const size_t rowb = (size_t)b * LTOK;

    for (int i = tid; i < TCH * 32; i += 256) {
        const int tr = min(t0 + (i >> 5), LTOK - 1);
        Ls[i] = dbc[(rowb + tr) * 64 + 32 + (i & 31)];
    }
    __syncthreads();

    float Ads[16];
#pragma unroll
    for (int s = 0; s < 16; ++s) Ads[s] = -__expf(A_log[d * DSTATE + s]);
    float h[16];
#pragma unroll
    for (int s = 0; s < 16; ++s)
        h[s] = hinit[((size_t)(b * CCH + c) * 16 + s) * DM + d];
    const float Dd = Dp[d];

    for (int t = t0; t < tend; ++t) {
        const size_t row = rowb + t;
        const float dtv = dt[row * DM + d];
        const float xcv = xc[row * DM + d];
        const float du = dtv * xcv;
        const float* Bp = &Ls[(t - t0) * 32];
        float p0 = 0.f, p1 = 0.f, p2 = 0.f, p3 = 0.f;
#pragma unroll
        for (int s = 0; s < 16; ++s) {
            const float dA = __expf(dtv * Ads[s]);
            const float hn = dA * h[s] + du * Bp[s];
            h[s] = hn;
            const float pc = hn * Bp[16 + s];
            if ((s & 3) == 0) p0 += pc;
            else if ((s & 3) == 1) p1 += pc;
            else if ((s & 3) == 2) p2 += pc;
            else p3 += pc;
        }
        const float y = (p0 + p1) + (p2 + p3) + xcv * Dd;
        const float z = bf2f(zbf[row * DM + d]);
        ym[row * DM + d] = (ushort_t)f2bf(y * (z * (1.f / (1.f + __expf(-z)))));
    }
}

// ---- LayerNorm over DM=512 per row; optional fp32 and bf16 outputs ----
__global__ __launch_bounds__(256) void ln_kernel(const float* __restrict__ in,
                                                 const float* __restrict__ w,
                                                 const float* __restrict__ bp,
                                                 float* __restrict__ outf,
                                                 ushort_t* __restrict__ outb)
{
    const int row = blockIdx.x;
    const int tid = threadIdx.x;
    const float2 v = *(const float2*)(in + (size_t)row * DM + tid * 2);
    float s  = v.x + v.y;
    float ss = v.x * v.x + v.y * v.y;
    for (int off = 32; off; off >>= 1) {
        s  += __shfl_down(s, off);
        ss += __shfl_down(ss, off);
    }
    __shared__ float sh[10];
    const int wid = tid >> 6, lane = tid & 63;
    if (lane == 0) { sh[wid] = s; sh[4 + wid] = ss; }
    __syncthreads();
    if (tid == 0) {
        float S = sh[0] + sh[1] + sh[2] + sh[3];
        float SS = sh[4] + sh[5] + sh[6] + sh[7];
        float mu = S / (float)DM;
        float var = SS / (float)DM - mu * mu;
        sh[8] = mu; sh[9] = rsqrtf(var + EPS_F);
    }
    __syncthreads();
    const float mu = sh[8], rstd = sh[9];
    const int c = tid * 2;
    float2 o;
    o.x = (v.x - mu) * rstd * w[c]     + bp[c];
    o.y = (v.y - mu) * rstd * w[c + 1] + bp[c + 1];
    if (outf) *(float2*)(outf + (size_t)row * DM + c) = o;
    if (outb) {
        unsigned pk = (unsigned)(ushort_t)f2bf(o.x) | ((unsigned)(ushort_t)f2bf(o.y) << 16);
        ((unsigned*)outb)[(size_t)row * (DM / 2) + tid] = pk;
    }
}

// =====================================================================
static inline void launch_gemm(hipStream_t st, const ushort_t* A, int lda,
                               const ushort_t* W, int ldw, const float* bias,
                               const float* resf, const ushort_t* resb,
                               float* outf, ushort_t* outb, int ldo,
                               int M, int N, int K, int rev, int act, int mode = 0,
                               const float* fstd = nullptr, const float* fmean = nullptr)
{
    dim3 g((N + 127) / 128, (M + 127) / 128);
    hipLaunchKernelGGL(gemm_bf16, g, dim3(256), 0, st,
                       A, lda, W, ldw, bias, resf, resb, outf, outb, ldo,
                       M, N, K, rev, act, mode, fstd, fmean);
}

extern "C" void kernel_launch(void* const* d_in, const int* in_sizes, int n_in,
                              void* d_out, int out_size, void* d_ws, size_t ws_size,
                              hipStream_t stream)
{
    const float* x_enc   = (const float*)d_in[0];
    const float* x_mark  = (const float*)d_in[1];
    const float* emb_W   = (const float*)d_in[4];
    const float* emb_b   = (const float*)d_in[5];
    const float* m_in_W[2]    = { (const float*)d_in[6],  (const float*)d_in[15] };
    const float* m_conv_W[2]  = { (const float*)d_in[7],  (const float*)d_in[16] };
    const float* m_conv_b[2]  = { (const float*)d_in[8],  (const float*)d_in[17] };
    const float* m_xproj_W[2] = { (const float*)d_in[9],  (const float*)d_in[18] };
    const float* m_dt_W[2]    = { (const float*)d_in[10], (const float*)d_in[19] };
    const float* m_dt_b[2]    = { (const float*)d_in[11], (const float*)d_in[20] };
    const float* m_A_log[2]   = { (const float*)d_in[12], (const float*)d_in[21] };
    const float* m_D[2]       = { (const float*)d_in[13], (const float*)d_in[22] };
    const float* m_out_W[2]   = { (const float*)d_in[14], (const float*)d_in[23] };
    const float* conv1_W = (const float*)d_in[24];
    const float* conv1_b = (const float*)d_in[25];
    const float* conv2_W = (const float*)d_in[26];
    const float* conv2_b = (const float*)d_in[27];
    const float* ln1_w = (const float*)d_in[28];
    const float* ln1_b = (const float*)d_in[29];
    const float* ln2_w = (const float*)d_in[30];
    const float* ln2_b = (const float*)d_in[31];
    const float* enc_w = (const float*)d_in[32];
    const float* enc_b = (const float*)d_in[33];
    const float* proj_W = (const float*)d_in[34];
    const float* proj_b = (const float*)d_in[35];

    const size_t MD = (size_t)MROWS * DM;        // 7,094,272
    float* ws = (float*)d_ws;
    size_t o = 0;
    float* means = ws + o; o += 13824;
    float* stdev = ws + o; o += 13824;
    float* xbuf  = ws + o; o += MD;              // x residual (fp32)
    float* accb  = ws + o; o += MD;              // accumulator (fp32)
    float* xib   = ws + o; o += MD;              // xi fp32; ALIAS: aprod/hinit, x2 fp32
    float* xcb   = ws + o; o += MD;              // xc fp32 (scan input)
    float* dtb   = ws + o; o += MD;              // dt fp32 (scan input)
    float* dbcb  = ws + o; o += (size_t)MROWS * 64;
    float* hpart = ws + o; o += (size_t)BATCH * CCH * 16 * DM;  // 4,194,304
    float* aprod = xib;                          // scan summaries alias xi
    float* x2f   = xib;                          // LN1 fp32 out alias (post-scan)

    ushort_t* wsb = (ushort_t*)(ws + o);
    size_t so = 0;
    ushort_t* xbuf_bf = wsb + so; so += MD;
    ushort_t* xcb_bf  = wsb + so; so += MD;
    ushort_t* ybuf_bf = wsb + so; so += MD;      // scan out; ALIAS: ffn hidden
    ushort_t* x2_bf   = wsb + so; so += MD;      // LN1/final-LN out; ALIAS: tok
    ushort_t* zbf     = wsb + so; so += MD;      // z gate (bf16)
    ushort_t* dbcb_bf = wsb + so; so += (size_t)MROWS * 64;
    ushort_t* embW_bf = wsb + so; so += 49152;
    ushort_t* inW_bf[2];  inW_bf[0] = wsb + so; so += 1048576; inW_bf[1] = wsb + so; so += 1048576;
    ushort_t* xpW_bf[2];  xpW_bf[0] = wsb + so; so += 65536;   xpW_bf[1] = wsb + so; so += 65536;
    ushort_t* dtW_bf[2];  dtW_bf[0] = wsb + so; so += 32768;   dtW_bf[1] = wsb + so; so += 32768;
    ushort_t* outW_bf[2]; outW_bf[0] = wsb + so; so += 524288; outW_bf[1] = wsb + so; so += 524288;
    ushort_t* c1W_bf = wsb + so; so += 524288;
    ushort_t* c2W_bf = wsb + so; so += 524288;
    ushort_t* projW_bf = wsb + so; so += 49152;
    ushort_t* tok_bf = x2_bf;                    // tok dead before LN1 writes x2
    ushort_t* hbuf_bf = ybuf_bf;                 // ffn hidden after ybuf consumed

    // 0) weight conversion (every launch; graph-safe, ~10 us)
    CvtJobs jobs;
    jobs.src[0] = emb_W;      jobs.dst[0] = embW_bf;    jobs.n[0] = 49152;
    jobs.src[1] = m_in_W[0];  jobs.dst[1] = inW_bf[0];  jobs.n[1] = 1048576;
    jobs.src[2] = m_in_W[1];  jobs.dst[2] = inW_bf[1];  jobs.n[2] = 1048576;
    jobs.src[3] = m_xproj_W[0]; jobs.dst[3] = xpW_bf[0]; jobs.n[3] = 65536;
    jobs.src[4] = m_xproj_W[1]; jobs.dst[4] = xpW_bf[1]; jobs.n[4] = 65536;
    jobs.src[5] = m_dt_W[0];  jobs.dst[5] = dtW_bf[0];  jobs.n[5] = 32768;
    jobs.src[6] = m_dt_W[1];  jobs.dst[6] = dtW_bf[1];  jobs.n[6] = 32768;
    jobs.src[7] = m_out_W[0]; jobs.dst[7] = outW_bf[0]; jobs.n[7] = 524288;
    jobs.src[8] = m_out_W[1]; jobs.dst[8] = outW_bf[1]; jobs.n[8] = 524288;
    jobs.src[9] = conv1_W;    jobs.dst[9] = c1W_bf;     jobs.n[9] = 524288;
    jobs.src[10] = conv2_W;   jobs.dst[10] = c2W_bf;    jobs.n[10] = 524288;
    jobs.src[11] = proj_W;    jobs.dst[11] = projW_bf;  jobs.n[11] = 49152;
    hipLaunchKernelGGL(cvt_kernel, dim3(64, 12), dim3(256), 0, stream, jobs);

    // 1) stats + token matrix + embedding
    hipLaunchKernelGGL(stats_kernel, dim3((BATCH * NVARS + 255) / 256), dim3(256), 0, stream,
                       x_enc, means, stdev);
    hipLaunchKernelGGL(tok_kernel, dim3((MROWS * SEQ + 255) / 256), dim3(256), 0, stream,
                       x_enc, x_mark, means, stdev, tok_bf);
    launch_gemm(stream, tok_bf, SEQ, embW_bf, SEQ, emb_b, nullptr, nullptr,
                xbuf, xbuf_bf, DM, MROWS, DM, SEQ, 0, 0);

    // 2) encoder layers
    for (int l = 0; l < 2; ++l) {
        for (int dir = 0; dir < 2; ++dir) {   // 0 = fwd (mf), 1 = rev (mr)
            const ushort_t* inW  = inW_bf[dir]  + (size_t)l * 2 * DM * DM;
            const float* cW   = m_conv_W[dir]  + (size_t)l * DM * 2;
            const float* cb   = m_conv_b[dir]  + (size_t)l * DM;
            const ushort_t* xpW  = xpW_bf[dir] + (size_t)l * 64 * DM;
            const ushort_t* dtW  = dtW_bf[dir] + (size_t)l * DM * DTRANK;
            const float* dtbias = m_dt_b[dir]  + (size_t)l * DM;
            const float* Alog = m_A_log[dir]   + (size_t)l * DM * DSTATE;
            const float* Dp   = m_D[dir]       + (size_t)l * DM;
            const ushort_t* outW = outW_bf[dir] + (size_t)l * DM * DM;

            // xz = x(rev?) @ in_W.T  -> xi fp32 + z bf16 (split)
            launch_gemm(stream, xbuf_bf, DM, inW, DM, nullptr, nullptr, nullptr,
                        xib, zbf, 0, MROWS, 2 * DM, DM, dir, 0, 2);
            // xc = silu(causal_conv(xi))
            hipLaunchKernelGGL(conv_silu_kernel, dim3((MROWS * DM + 255) / 256), dim3(256),
                               0, stream, xib, xcb, xcb_bf, cW, cb);
            // dbc = xc @ xproj_W.T   (M x 64)
            launch_gemm(stream, xcb_bf, DM, xpW, DM, nullptr, nullptr, nullptr,
                        dbcb, dbcb_bf, 64, MROWS, 64, DM, 0, 0);
            // dt = softplus(dtr @ dt_W.T + dt_b)   (M x 512)
            launch_gemm(stream, dbcb_bf, 64, dtW, DTRANK, dtbias, nullptr, nullptr,
                        dtb, nullptr, DM, MROWS, DM, DTRANK, 0, 2);
            // selective scan: 3-pass chunked parallel scan (aprod aliases xib)
            hipLaunchKernelGGL(scan1_kernel, dim3(2, CCH, BATCH), dim3(256), 0, stream,
                               xcb, dtb, dbcb, Alog, aprod, hpart);
            hipLaunchKernelGGL(scan2_kernel, dim3((BATCH * 16 * DM) / 256), dim3(256), 0, stream,
                               aprod, hpart);
            hipLaunchKernelGGL(scan3_kernel, dim3(2, CCH, BATCH), dim3(256), 0, stream,
                               xcb, dtb, dbcb, zbf, Alog, Dp, aprod, ybuf_bf);
            // acc = (dir==0 ? x : acc) + ym(rev?) @ out_W.T
            launch_gemm(stream, ybuf_bf, DM, outW, DM, nullptr,
                        dir == 0 ? xbuf : accb, nullptr,
                        accb, nullptr, DM, MROWS, DM, DM, dir, 0);
        }
        // x2 = LN1(acc)  (fp32 for ffn residual + bf16 for GEMM A)
        hipLaunchKernelGGL(ln_kernel, dim3(MROWS), dim3(256), 0, stream,
                           accb, ln1_w + l * DM, ln1_b + l * DM, x2f, x2_bf);
        // h = relu(x2 @ conv1_W.T + b1)   (bf16 only)
        launch_gemm(stream, x2_bf, DM, c1W_bf + (size_t)l * DFF * DM, DM,
                    conv1_b + l * DFF, nullptr, nullptr,
                    nullptr, hbuf_bf, DFF, MROWS, DFF, DM, 0, 1);
        // acc = x2 + h @ conv2_W.T + b2
        launch_gemm(stream, hbuf_bf, DFF, c2W_bf + (size_t)l * DM * DFF, DFF,
                    conv2_b + l * DM, x2f, nullptr,
                    accb, nullptr, DM, MROWS, DM, DFF, 0, 0);
        // x = LN2(acc)
        hipLaunchKernelGGL(ln_kernel, dim3(MROWS), dim3(256), 0, stream,
                           accb, ln2_w + l * DM, ln2_b + l * DM, xbuf, xbuf_bf);
    }

    // 3) final norm + projection + de-norm (transposed write into d_out)
    hipLaunchKernelGGL(ln_kernel, dim3(MROWS), dim3(256), 0, stream,
                       xbuf, enc_w, enc_b, nullptr, x2_bf);
    launch_gemm(stream, x2_bf, DM, projW_bf, DM, proj_b, nullptr, nullptr,
                (float*)d_out, nullptr, 0, MROWS, PRED, DM, 0, 0, 1, stdev, means);
}

// Round 6
// 3142.722 us; speedup vs baseline: 1.0117x; 1.0117x over previous
//
#include <hip/hip_runtime.h>
#include <math.h>

// ---- problem constants ----
#define BATCH   16
#define SEQ     96
#define NVARS   862
#define NMARK   4
#define LTOK    866          // NVARS + NMARK
#define MROWS   (BATCH*LTOK) // 13856
#define DM      512
#define DSTATE  16
#define DTRANK  32
#define DFF     512
#define PRED    96
#define EPS_F   1e-5f

// chunked parallel scan
#define CCH     32           // chunks per sequence
#define TCH     28           // steps per chunk (32*28=896 >= 866)

typedef __attribute__((ext_vector_type(4))) float f32x4;
typedef __attribute__((ext_vector_type(8))) short bf16x8;  // 8 bf16 in 4 VGPRs
typedef unsigned short ushort_t;

__device__ __forceinline__ short f2bf(float f) {
    unsigned u = __builtin_bit_cast(unsigned, f);
    u += 0x7fffu + ((u >> 16) & 1u);          // round-to-nearest-even
    return (short)(u >> 16);
}
__device__ __forceinline__ float bf2f(ushort_t u) {
    return __builtin_bit_cast(float, (unsigned)u << 16);
}

// =====================================================================
// bf16 GEMM, register-staged (R4 structure + bf16 inputs + swizzled LDS):
//   out = act(A . W^T + bias) + res
// A bf16 row-major (lda), W bf16 row-major (N x ldw). Tile 128x128, BK=32,
// 256 thr = 4 waves (2x2), each wave 64x64 via 4x4 frags of 16x16x32.
// Staging: thread -> row=tid>>1, half=tid&1; two bf16x8 global loads per
// matrix, ds_write_b128 at XOR-swizzled column group c^((row>>1)&3).
// Frag reads use the same swizzle -> measured-conflict-free (round 5).
// Grid is 1-D linearized with bijective XCD swizzle (m204) so blocks
// sharing an A panel land on the same XCD's L2.
// rev: A rows reversed within each LTOK segment (clamped at edges).
// mode: 0 = normal (outf fp32 and/or outb bf16, stride ldo)
//       1 = final: denormed transposed write into d_out (B, PRED, NVARS)
//       2 = split xz: cols<512 -> outf (xi fp32), cols>=512 -> outb (z bf16)
// K multiple of 32. Row starts 16B-aligned (all lda/ldw multiples of 8).
// =====================================================================
__global__ __launch_bounds__(256) void gemm_bf16(
    const ushort_t* __restrict__ A, int lda,
    const ushort_t* __restrict__ W, int ldw,
    const float* __restrict__ bias,
    const float* __restrict__ resf, const ushort_t* __restrict__ resb,
    float* __restrict__ outf, ushort_t* __restrict__ outb, int ldo,
    int M, int N, int K, int rev, int act, int mode, int gx,
    const float* __restrict__ fstd, const float* __restrict__ fmean)
{
    __shared__ ushort_t Als[128 * 32];
    __shared__ ushort_t Bls[128 * 32];
    const int tid  = threadIdx.x;
    const int lane = tid & 63;
    const int w    = tid >> 6;
    const int wm   = w >> 1;          // wave row (0..1)
    const int wn   = w & 1;           // wave col (0..1)

    // bijective XCD swizzle (m204): consecutive dispatch ids (round-robin
    // across 8 XCDs) -> same XCD gets a contiguous tile range.
    const int nwg = gridDim.x;
    const int orig = blockIdx.x;
    const int q = nwg >> 3, r = nwg & 7;
    const int xcd = orig & 7, idx = orig >> 3;
    const int swz = (xcd < r ? xcd * (q + 1) : r * (q + 1) + (xcd - r) * q) + idx;
    const int m0 = (swz / gx) * 128, n0 = (swz % gx) * 128;

    // staging geometry
    const int srow = tid >> 1;        // 0..127
    const int sh   = tid & 1;         // which 16-col half
    int gm = m0 + srow; if (gm > M - 1) gm = M - 1;
    int rm = gm;
    if (rev) { int b = gm / LTOK; int t = gm - b * LTOK; rm = b * LTOK + (LTOK - 1 - t); }
    const size_t aoff = (size_t)rm * lda + sh * 16;
    int gn = n0 + srow; if (gn > N - 1) gn = N - 1;
    const size_t woff = (size_t)gn * ldw + sh * 16;
    const int swz0 = ((sh * 2 + 0) ^ ((srow >> 1) & 3)) * 8;
    const int swz1 = ((sh * 2 + 1) ^ ((srow >> 1) & 3)) * 8;
    ushort_t* Awp = &Als[srow * 32];
    ushort_t* Bwp = &Bls[srow * 32];

    f32x4 acc[4][4];
#pragma unroll
    for (int i = 0; i < 4; ++i)
#pragma unroll
        for (int j = 0; j < 4; ++j) { f32x4 z = {0.f, 0.f, 0.f, 0.f}; acc[i][j] = z; }

    const int fr = lane & 15;         // frag row (A) / col (B)
    const int kg = lane >> 4;         // k-group 0..3
    const int cg = (kg ^ ((fr >> 1) & 3)) * 8;  // swizzled LDS column offset

    for (int k0 = 0; k0 < K; k0 += 32) {
        const bf16x8 a0 = *(const bf16x8*)(A + aoff + k0);
        const bf16x8 a1 = *(const bf16x8*)(A + aoff + k0 + 8);
        const bf16x8 b0 = *(const bf16x8*)(W + woff + k0);
        const bf16x8 b1 = *(const bf16x8*)(W + woff + k0 + 8);
        __syncthreads();              // prior frag reads done before overwrite
        *(bf16x8*)(Awp + swz0) = a0;
        *(bf16x8*)(Awp + swz1) = a1;
        *(bf16x8*)(Bwp + swz0) = b0;
        *(bf16x8*)(Bwp + swz1) = b1;
        __syncthreads();

        bf16x8 a4[4], b4[4];
#pragma unroll
        for (int i = 0; i < 4; ++i) {
            a4[i] = *(const bf16x8*)&Als[(wm * 64 + i * 16 + fr) * 32 + cg];
            b4[i] = *(const bf16x8*)&Bls[(wn * 64 + i * 16 + fr) * 32 + cg];
        }
#pragma unroll
        for (int mi = 0; mi < 4; ++mi)
#pragma unroll
            for (int ni = 0; ni < 4; ++ni)
                acc[mi][ni] = __builtin_amdgcn_mfma_f32_16x16x32_bf16(
                    a4[mi], b4[ni], acc[mi][ni], 0, 0, 0);
    }

    // epilogue: C/D layout col=lane&15, row=(lane>>4)*4+j   [m89-verified]
#pragma unroll
    for (int mi = 0; mi < 4; ++mi) {
#pragma unroll
        for (int ni = 0; ni < 4; ++ni) {
            const int gnn = n0 + wn * 64 + ni * 16 + fr;
            if (gnn >= N) continue;
#pragma unroll
            for (int j = 0; j < 4; ++j) {
                const int gmm = m0 + wm * 64 + mi * 16 + kg * 4 + j;
                if (gmm >= M) continue;
                float v = acc[mi][ni][j];
                if (bias) v += bias[gnn];
                if (act == 1) v = fmaxf(v, 0.f);
                else if (act == 2) v = (v > 20.f) ? v : log1pf(__expf(v)); // softplus
                if (resf) v += resf[(size_t)gmm * DM + gnn];
                else if (resb) v += bf2f(resb[(size_t)gmm * DM + gnn]);
                if (mode == 0) {
                    if (outf) outf[(size_t)gmm * ldo + gnn] = v;
                    if (outb) outb[(size_t)gmm * ldo + gnn] = (ushort_t)f2bf(v);
                } else if (mode == 2) {
                    if (gnn < DM) outf[(size_t)gmm * DM + gnn] = v;
                    else         outb[(size_t)gmm * DM + gnn - DM] = (ushort_t)f2bf(v);
                } else {
                    const int bb = gmm / LTOK, vv = gmm - bb * LTOK;
                    if (vv < NVARS) {
                        outf[((size_t)bb * PRED + gnn) * NVARS + vv] =
                            v * fstd[bb * NVARS + vv] + fmean[bb * NVARS + vv];
                    }
                }
            }
        }
    }
}

// ---- fp32 -> bf16 weight conversion, 12 jobs in one kernel ----
struct CvtJobs {
    const float* src[12];
    ushort_t*    dst[12];
    int          n[12];
};
__global__ void cvt_kernel(CvtJobs jobs) {
    const int j = blockIdx.y;
    const float* s = jobs.src[j];
    ushort_t* d = jobs.dst[j];
    const int n = jobs.n[j];
    for (int i = blockIdx.x * blockDim.x + threadIdx.x; i < n; i += gridDim.x * blockDim.x)
        d[i] = (ushort_t)f2bf(s[i]);
}

// ---- per-(b,var) mean / stdev over SEQ ----
__global__ void stats_kernel(const float* __restrict__ x_enc,
                             float* __restrict__ means, float* __restrict__ stdev)
{
    int i = blockIdx.x * blockDim.x + threadIdx.x;
    if (i >= BATCH * NVARS) return;
    int b = i / NVARS, v = i - b * NVARS;
    const float* p = x_enc + (size_t)b * SEQ * NVARS + v;
    float s = 0.f;
    for (int t = 0; t < SEQ; ++t) s += p[(size_t)t * NVARS];
    float mu = s / (float)SEQ;
    float ss = 0.f;
    for (int t = 0; t < SEQ; ++t) { float d = p[(size_t)t * NVARS] - mu; ss += d * d; }
    means[i] = mu;
    stdev[i] = sqrtf(ss / (float)SEQ + EPS_F);
}

// ---- build token matrix (MROWS x SEQ) in bf16 ----
__global__ void tok_kernel(const float* __restrict__ x_enc, const float* __restrict__ x_mark,
                           const float* __restrict__ means, const float* __restrict__ stdev,
                           ushort_t* __restrict__ tok)
{
    int i = blockIdx.x * blockDim.x + threadIdx.x;
    if (i >= MROWS * SEQ) return;
    int s = i % SEQ;
    int row = i / SEQ;
    int b = row / LTOK, l = row - b * LTOK;
    float val;
    if (l < NVARS) {
        val = (x_enc[((size_t)b * SEQ + s) * NVARS + l] - means[b * NVARS + l])
              / stdev[b * NVARS + l];
    } else {
        val = x_mark[((size_t)b * SEQ + s) * NMARK + (l - NVARS)];
    }
    tok[i] = (ushort_t)f2bf(val);
}

// ---- causal depthwise conv (width 2) + SiLU; xi (MROWS x 512) fp32 ----
__global__ void conv_silu_kernel(const float* __restrict__ xi, float* __restrict__ xc,
                                 ushort_t* __restrict__ xc_bf,
                                 const float* __restrict__ cW, const float* __restrict__ cb)
{
    int i = blockIdx.x * blockDim.x + threadIdx.x;
    if (i >= MROWS * DM) return;
    int d = i & (DM - 1);
    int row = i >> 9;
    int t = row % LTOK;
    float cur = xi[i];
    float prev = (t == 0) ? 0.f : xi[i - DM];
    float v = prev * cW[d * 2 + 0] + cur * cW[d * 2 + 1] + cb[d];
    float sv = v * (1.f / (1.f + __expf(-v)));   // silu
    xc[i] = sv;
    xc_bf[i] = (ushort_t)f2bf(sv);
}

// =====================================================================
// Chunked parallel selective scan (3 passes), one-lane-per-channel.
// =====================================================================
__global__ __launch_bounds__(256) void scan1_kernel(
    const float* __restrict__ xc, const float* __restrict__ dt,
    const float* __restrict__ dbc, const float* __restrict__ A_log,
    float* __restrict__ aprod, float* __restrict__ hpart)
{
    __shared__ float Ls[TCH * 32];
    const int tid = threadIdx.x;
    const int d = blockIdx.x * 256 + tid;
    const int c = blockIdx.y;
    const int b = blockIdx.z;
    const int t0 = c * TCH;
    const int tend = min(t0 + TCH, LTOK);
    const size_t rowb = (size_t)b * LTOK;

    for (int i = tid; i < TCH * 32; i += 256) {
        const int tr = min(t0 + (i >> 5), LTOK - 1);
        Ls[i] = dbc[(rowb + tr) * 64 + 32 + (i & 31)];
    }
    __syncthreads();

    float Ads[16];
#pragma unroll
    for (int s = 0; s < 16; ++s) Ads[s] = -__expf(A_log[d * DSTATE + s]);
    float h[16];
#pragma unroll
    for (int s = 0; s < 16; ++s) h[s] = 0.f;
    float sumdt = 0.f;

    for (int t = t0; t < tend; ++t) {
        const size_t row = rowb + t;
        const float dtv = dt[row * DM + d];
        const float xcv = xc[row * DM + d];
        const float du = dtv * xcv;
        sumdt += dtv;
        const float* Bp = &Ls[(t - t0) * 32];
#pragma unroll
        for (int s = 0; s < 16; ++s) {
            const float dA = __expf(dtv * Ads[s]);
            h[s] = dA * h[s] + du * Bp[s];
        }
    }
#pragma unroll
    for (int s = 0; s < 16; ++s) {
        const size_t oidx = ((size_t)(b * CCH + c) * 16 + s) * DM + d;
        aprod[oidx] = __expf(Ads[s] * sumdt);
        hpart[oidx] = h[s];
    }
}

// scan2: sequential combine over chunks; writes hinit IN-PLACE into aprod.
__global__ __launch_bounds__(256) void scan2_kernel(
    float* __restrict__ aprod, const float* __restrict__ hpart)
{
    const int gid = blockIdx.x * 256 + threadIdx.x;   // BATCH*16*DM = 131072
    const int d = gid & (DM - 1);
    const int s = (gid >> 9) & 15;
    const int b = gid >> 13;
    float h = 0.f;
    for (int c = 0; c < CCH; ++c) {
        const size_t idx = ((size_t)(b * CCH + c) * 16 + s) * DM + d;
        const float ap = aprod[idx];
        const float hp = hpart[idx];
        aprod[idx] = h;               // hinit
        h = hp + ap * h;
    }
}

__global__ __launch_bounds__(256) void scan3_kernel(
    const float* __restrict__ xc, const float* __restrict__ dt,
    const float* __restrict__ dbc, const ushort_t* __restrict__ zbf,
    const float* __restrict__ A_log, const float* __restrict__ Dp,
    const float* __restrict__ hinit, ushort_t* __restrict__ ym)
{
    __shared__ float Ls[TCH * 32];
    const int tid = threadIdx.x;
    const int d = blockIdx.x * 256 + tid;
    const int c = blockIdx.y;
    const int b = blockIdx.z;
    const int t0 = c * TCH;
    const int tend = min(t0 + TCH, LTOK);
    const size_t rowb = (size_t)b * LTOK;

    for (int i = tid; i < TCH * 32; i += 256) {
        const int tr = min(t0 + (i >> 5), LTOK - 1);
        Ls[i] = dbc[(rowb + tr) * 64 + 32 + (i & 31)];
    }
    __syncthreads();

    float Ads[16];
#pragma unroll
    for (int s = 0; s < 16; ++s) Ads[s] = -__expf(A_log[d * DSTATE + s]);
    float h[16];
#pragma unroll
    for (int s = 0; s < 16; ++s)
        h[s] = hinit[((size_t)(b * CCH + c) * 16 + s) * DM + d];
    const float Dd = Dp[d];

    for (int t = t0; t < tend; ++t) {
        const size_t row = rowb + t;
        const float dtv = dt[row * DM + d];
        const float xcv = xc[row * DM + d];
        const float du = dtv * xcv;
        const float* Bp = &Ls[(t - t0) * 32];
        float p0 = 0.f, p1 = 0.f, p2 = 0.f, p3 = 0.f;
#pragma unroll
        for (int s = 0; s < 16; ++s) {
            const float dA = __expf(dtv * Ads[s]);
            const float hn = dA * h[s] + du * Bp[s];
            h[s] = hn;
            const float pc = hn * Bp[16 + s];
            if ((s & 3) == 0) p0 += pc;
            else if ((s & 3) == 1) p1 += pc;
            else if ((s & 3) == 2) p2 += pc;
            else p3 += pc;
        }
        const float y = (p0 + p1) + (p2 + p3) + xcv * Dd;
        const float z = bf2f(zbf[row * DM + d]);
        ym[row * DM + d] = (ushort_t)f2bf(y * (z * (1.f / (1.f + __expf(-z)))));
    }
}

// ---- LayerNorm over DM=512 per row; optional fp32 and bf16 outputs ----
__global__ __launch_bounds__(256) void ln_kernel(const float* __restrict__ in,
                                                 const float* __restrict__ w,
                                                 const float* __restrict__ bp,
                                                 float* __restrict__ outf,
                                                 ushort_t* __restrict__ outb)
{
    const int row = blockIdx.x;
    const int tid = threadIdx.x;
    const float2 v = *(const float2*)(in + (size_t)row * DM + tid * 2);
    float s  = v.x + v.y;
    float ss = v.x * v.x + v.y * v.y;
    for (int off = 32; off; off >>= 1) {
        s  += __shfl_down(s, off);
        ss += __shfl_down(ss, off);
    }
    __shared__ float sh[10];
    const int wid = tid >> 6, lane = tid & 63;
    if (lane == 0) { sh[wid] = s; sh[4 + wid] = ss; }
    __syncthreads();
    if (tid == 0) {
        float S = sh[0] + sh[1] + sh[2] + sh[3];
        float SS = sh[4] + sh[5] + sh[6] + sh[7];
        float mu = S / (float)DM;
        float var = SS / (float)DM - mu * mu;
        sh[8] = mu; sh[9] = rsqrtf(var + EPS_F);
    }
    __syncthreads();
    const float mu = sh[8], rstd = sh[9];
    const int c = tid * 2;
    float2 o;
    o.x = (v.x - mu) * rstd * w[c]     + bp[c];
    o.y = (v.y - mu) * rstd * w[c + 1] + bp[c + 1];
    if (outf) *(float2*)(outf + (size_t)row * DM + c) = o;
    if (outb) {
        unsigned pk = (unsigned)(ushort_t)f2bf(o.x) | ((unsigned)(ushort_t)f2bf(o.y) << 16);
        ((unsigned*)outb)[(size_t)row * (DM / 2) + tid] = pk;
    }
}

// =====================================================================
static inline void launch_gemm(hipStream_t st, const ushort_t* A, int lda,
                               const ushort_t* W, int ldw, const float* bias,
                               const float* resf, const ushort_t* resb,
                               float* outf, ushort_t* outb, int ldo,
                               int M, int N, int K, int rev, int act, int mode = 0,
                               const float* fstd = nullptr, const float* fmean = nullptr)
{
    const int gx = (N + 127) / 128, gy = (M + 127) / 128;
    hipLaunchKernelGGL(gemm_bf16, dim3(gx * gy), dim3(256), 0, st,
                       A, lda, W, ldw, bias, resf, resb, outf, outb, ldo,
                       M, N, K, rev, act, mode, gx, fstd, fmean);
}

extern "C" void kernel_launch(void* const* d_in, const int* in_sizes, int n_in,
                              void* d_out, int out_size, void* d_ws, size_t ws_size,
                              hipStream_t stream)
{
    const float* x_enc   = (const float*)d_in[0];
    const float* x_mark  = (const float*)d_in[1];
    const float* emb_W   = (const float*)d_in[4];
    const float* emb_b   = (const float*)d_in[5];
    const float* m_in_W[2]    = { (const float*)d_in[6],  (const float*)d_in[15] };
    const float* m_conv_W[2]  = { (const float*)d_in[7],  (const float*)d_in[16] };
    const float* m_conv_b[2]  = { (const float*)d_in[8],  (const float*)d_in[17] };
    const float* m_xproj_W[2] = { (const float*)d_in[9],  (const float*)d_in[18] };
    const float* m_dt_W[2]    = { (const float*)d_in[10], (const float*)d_in[19] };
    const float* m_dt_b[2]    = { (const float*)d_in[11], (const float*)d_in[20] };
    const float* m_A_log[2]   = { (const float*)d_in[12], (const float*)d_in[21] };
    const float* m_D[2]       = { (const float*)d_in[13], (const float*)d_in[22] };
    const float* m_out_W[2]   = { (const float*)d_in[14], (const float*)d_in[23] };
    const float* conv1_W = (const float*)d_in[24];
    const float* conv1_b = (const float*)d_in[25];
    const float* conv2_W = (const float*)d_in[26];
    const float* conv2_b = (const float*)d_in[27];
    const float* ln1_w = (const float*)d_in[28];
    const float* ln1_b = (const float*)d_in[29];
    const float* ln2_w = (const float*)d_in[30];
    const float* ln2_b = (const float*)d_in[31];
    const float* enc_w = (const float*)d_in[32];
    const float* enc_b = (const float*)d_in[33];
    const float* proj_W = (const float*)d_in[34];
    const float* proj_b = (const float*)d_in[35];

    const size_t MD = (size_t)MROWS * DM;        // 7,094,272
    float* ws = (float*)d_ws;
    size_t o = 0;
    float* means = ws + o; o += 13824;
    float* stdev = ws + o; o += 13824;
    float* xbuf  = ws + o; o += MD;              // x residual (fp32)
    float* accb  = ws + o; o += MD;              // accumulator (fp32)
    float* xib   = ws + o; o += MD;              // xi fp32; ALIAS: aprod/hinit, x2 fp32
    float* xcb   = ws + o; o += MD;              // xc fp32 (scan input)
    float* dtb   = ws + o; o += MD;              // dt fp32 (scan input)
    float* dbcb  = ws + o; o += (size_t)MROWS * 64;
    float* hpart = ws + o; o += (size_t)BATCH * CCH * 16 * DM;  // 4,194,304
    float* aprod = xib;                          // scan summaries alias xi
    float* x2f   = xib;                          // LN1 fp32 out alias (post-scan)

    ushort_t* wsb = (ushort_t*)(ws + o);
    size_t so = 0;
    ushort_t* xbuf_bf = wsb + so; so += MD;
    ushort_t* xcb_bf  = wsb + so; so += MD;
    ushort_t* ybuf_bf = wsb + so; so += MD;      // scan out; ALIAS: ffn hidden
    ushort_t* x2_bf   = wsb + so; so += MD;      // LN1/final-LN out; ALIAS: tok
    ushort_t* zbf     = wsb + so; so += MD;      // z gate (bf16)
    ushort_t* dbcb_bf = wsb + so; so += (size_t)MROWS * 64;
    ushort_t* embW_bf = wsb + so; so += 49152;
    ushort_t* inW_bf[2];  inW_bf[0] = wsb + so; so += 1048576; inW_bf[1] = wsb + so; so += 1048576;
    ushort_t* xpW_bf[2];  xpW_bf[0] = wsb + so; so += 65536;   xpW_bf[1] = wsb + so; so += 65536;
    ushort_t* dtW_bf[2];  dtW_bf[0] = wsb + so; so += 32768;   dtW_bf[1] = wsb + so; so += 32768;
    ushort_t* outW_bf[2]; outW_bf[0] = wsb + so; so += 524288; outW_bf[1] = wsb + so; so += 524288;
    ushort_t* c1W_bf = wsb + so; so += 524288;
    ushort_t* c2W_bf = wsb + so; so += 524288;
    ushort_t* projW_bf = wsb + so; so += 49152;
    ushort_t* tok_bf = x2_bf;                    // tok dead before LN1 writes x2
    ushort_t* hbuf_bf = ybuf_bf;                 // ffn hidden after ybuf consumed

    // 0) weight conversion (every launch; graph-safe)
    CvtJobs jobs;
    jobs.src[0] = emb_W;      jobs.dst[0] = embW_bf;    jobs.n[0] = 49152;
    jobs.src[1] = m_in_W[0];  jobs.dst[1] = inW_bf[0];  jobs.n[1] = 1048576;
    jobs.src[2] = m_in_W[1];  jobs.dst[2] = inW_bf[1];  jobs.n[2] = 1048576;
    jobs.src[3] = m_xproj_W[0]; jobs.dst[3] = xpW_bf[0]; jobs.n[3] = 65536;
    jobs.src[4] = m_xproj_W[1]; jobs.dst[4] = xpW_bf[1]; jobs.n[4] = 65536;
    jobs.src[5] = m_dt_W[0];  jobs.dst[5] = dtW_bf[0];  jobs.n[5] = 32768;
    jobs.src[6] = m_dt_W[1];  jobs.dst[6] = dtW_bf[1];  jobs.n[6] = 32768;
    jobs.src[7] = m_out_W[0]; jobs.dst[7] = outW_bf[0]; jobs.n[7] = 524288;
    jobs.src[8] = m_out_W[1]; jobs.dst[8] = outW_bf[1]; jobs.n[8] = 524288;
    jobs.src[9] = conv1_W;    jobs.dst[9] = c1W_bf;     jobs.n[9] = 524288;
    jobs.src[10] = conv2_W;   jobs.dst[10] = c2W_bf;    jobs.n[10] = 524288;
    jobs.src[11] = proj_W;    jobs.dst[11] = projW_bf;  jobs.n[11] = 49152;
    hipLaunchKernelGGL(cvt_kernel, dim3(64, 12), dim3(256), 0, stream, jobs);

    // 1) stats + token matrix + embedding
    hipLaunchKernelGGL(stats_kernel, dim3((BATCH * NVARS + 255) / 256), dim3(256), 0, stream,
                       x_enc, means, stdev);
    hipLaunchKernelGGL(tok_kernel, dim3((MROWS * SEQ + 255) / 256), dim3(256), 0, stream,
                       x_enc, x_mark, means, stdev, tok_bf);
    launch_gemm(stream, tok_bf, SEQ, embW_bf, SEQ, emb_b, nullptr, nullptr,
                xbuf, xbuf_bf, DM, MROWS, DM, SEQ, 0, 0);

    // 2) encoder layers
    for (int l = 0; l < 2; ++l) {
        for (int dir = 0; dir < 2; ++dir) {   // 0 = fwd (mf), 1 = rev (mr)
            const ushort_t* inW  = inW_bf[dir]  + (size_t)l * 2 * DM * DM;
            const float* cW   = m_conv_W[dir]  + (size_t)l * DM * 2;
            const float* cb   = m_conv_b[dir]  + (size_t)l * DM;
            const ushort_t* xpW  = xpW_bf[dir] + (size_t)l * 64 * DM;
            const ushort_t* dtW  = dtW_bf[dir] + (size_t)l * DM * DTRANK;
            const float* dtbias = m_dt_b[dir]  + (size_t)l * DM;
            const float* Alog = m_A_log[dir]   + (size_t)l * DM * DSTATE;
            const float* Dp   = m_D[dir]       + (size_t)l * DM;
            const ushort_t* outW = outW_bf[dir] + (size_t)l * DM * DM;

            // xz = x(rev?) @ in_W.T  -> xi fp32 + z bf16 (split)
            launch_gemm(stream, xbuf_bf, DM, inW, DM, nullptr, nullptr, nullptr,
                        xib, zbf, 0, MROWS, 2 * DM, DM, dir, 0, 2);
            // xc = silu(causal_conv(xi))
            hipLaunchKernelGGL(conv_silu_kernel, dim3((MROWS * DM + 255) / 256), dim3(256),
                               0, stream, xib, xcb, xcb_bf, cW, cb);
            // dbc = xc @ xproj_W.T   (M x 64)
            launch_gemm(stream, xcb_bf, DM, xpW, DM, nullptr, nullptr, nullptr,
                        dbcb, dbcb_bf, 64, MROWS, 64, DM, 0, 0);
            // dt = softplus(dtr @ dt_W.T + dt_b)   (M x 512)
            launch_gemm(stream, dbcb_bf, 64, dtW, DTRANK, dtbias, nullptr, nullptr,
                        dtb, nullptr, DM, MROWS, DM, DTRANK, 0, 2);
            // selective scan: 3-pass chunked parallel scan (aprod aliases xib)
            hipLaunchKernelGGL(scan1_kernel, dim3(2, CCH, BATCH), dim3(256), 0, stream,
                               xcb, dtb, dbcb, Alog, aprod, hpart);
            hipLaunchKernelGGL(scan2_kernel, dim3((BATCH * 16 * DM) / 256), dim3(256), 0, stream,
                               aprod, hpart);
            hipLaunchKernelGGL(scan3_kernel, dim3(2, CCH, BATCH), dim3(256), 0, stream,
                               xcb, dtb, dbcb, zbf, Alog, Dp, aprod, ybuf_bf);
            // acc = (dir==0 ? x : acc) + ym(rev?) @ out_W.T
            launch_gemm(stream, ybuf_bf, DM, outW, DM, nullptr,
                        dir == 0 ? xbuf : accb, nullptr,
                        accb, nullptr, DM, MROWS, DM, DM, dir, 0);
        }
        // x2 = LN1(acc)  (fp32 for ffn residual + bf16 for GEMM A)
        hipLaunchKernelGGL(ln_kernel, dim3(MROWS), dim3(256), 0, stream,
                           accb, ln1_w + l * DM, ln1_b + l * DM, x2f, x2_bf);
        // h = relu(x2 @ conv1_W.T + b1)   (bf16 only)
        launch_gemm(stream, x2_bf, DM, c1W_bf + (size_t)l * DFF * DM, DM,
                    conv1_b + l * DFF, nullptr, nullptr,
                    nullptr, hbuf_bf, DFF, MROWS, DFF, DM, 0, 1);
        // acc = x2 + h @ conv2_W.T + b2
        launch_gemm(stream, hbuf_bf, DFF, c2W_bf + (size_t)l * DM * DFF, DFF,
                    conv2_b + l * DM, x2f, nullptr,
                    accb, nullptr, DM, MROWS, DM, DFF, 0, 0);
        // x = LN2(acc)
        hipLaunchKernelGGL(ln_kernel, dim3(MROWS), dim3(256), 0, stream,
                           accb, ln2_w + l * DM, ln2_b + l * DM, xbuf, xbuf_bf);
    }

    // 3) final norm + projection + de-norm (transposed write into d_out)
    hipLaunchKernelGGL(ln_kernel, dim3(MROWS), dim3(256), 0, stream,
                       xbuf, enc_w, enc_b, nullptr, x2_bf);
    launch_gemm(stream, x2_bf, DM, projW_bf, DM, proj_b, nullptr, nullptr,
                (float*)d_out, nullptr, 0, MROWS, PRED, DM, 0, 0, 1, stdev, means);
}

// Round 7
// 1582.855 us; speedup vs baseline: 2.0086x; 1.9855x over previous
//
#include <hip/hip_runtime.h>
#include <math.h>

// ---- problem constants ----
#define BATCH   16
#define SEQ     96
#define NVARS   862
#define NMARK   4
#define LTOK    866          // NVARS + NMARK
#define MROWS   (BATCH*LTOK) // 13856
#define DM      512
#define DSTATE  16
#define DTRANK  32
#define DFF     512
#define PRED    96
#define EPS_F   1e-5f

// chunked parallel scan
#define CCH     32           // chunks per sequence
#define TCH     28           // steps per chunk (32*28=896 >= 866)

typedef __attribute__((ext_vector_type(4))) float f32x4;
typedef __attribute__((ext_vector_type(8))) short bf16x8;  // 8 bf16 in 4 VGPRs
typedef unsigned short ushort_t;

__device__ __forceinline__ short f2bf(float f) {
    unsigned u = __builtin_bit_cast(unsigned, f);
    u += 0x7fffu + ((u >> 16) & 1u);          // round-to-nearest-even
    return (short)(u >> 16);
}
__device__ __forceinline__ float bf2f(ushort_t u) {
    return __builtin_bit_cast(float, (unsigned)u << 16);
}

// =====================================================================
// bf16 GEMM, register-staged, SINGLE fp32 output (R4-proven store path):
//   out = act(A . W^T + bias) + res
// A bf16 row-major (lda), W bf16 row-major (N x ldw). Tile 128x128, BK=32,
// 256 thr = 4 waves (2x2), each wave 64x64 via 4x4 frags of 16x16x32.
// Staging: row=tid>>1, half=tid&1; bf16x8 global loads, ds_write at
// XOR-swizzled col group c^((row>>1)&3); frag reads same swizzle
// (measured conflict-free, R5/R6). 1-D grid + bijective XCD swizzle (m204).
// rev: A rows reversed within each LTOK segment (clamped at edges).
// final_mode: denormed transposed write into d_out (B, PRED, NVARS).
// K multiple of 32 (or 96/32-step compatible); rows 16B-aligned.
// =====================================================================
__global__ __launch_bounds__(256) void gemm_bf16(
    const ushort_t* __restrict__ A, int lda,
    const ushort_t* __restrict__ W, int ldw,
    const float* __restrict__ bias,
    const float* __restrict__ res,
    float* __restrict__ out, int ldo,
    int M, int N, int K, int rev, int act, int final_mode, int gx,
    const float* __restrict__ fstd, const float* __restrict__ fmean)
{
    __shared__ ushort_t Als[128 * 32];
    __shared__ ushort_t Bls[128 * 32];
    const int tid  = threadIdx.x;
    const int lane = tid & 63;
    const int w    = tid >> 6;
    const int wm   = w >> 1;          // wave row (0..1)
    const int wn   = w & 1;           // wave col (0..1)

    // bijective XCD swizzle (m204)
    const int nwg = gridDim.x;
    const int orig = blockIdx.x;
    const int q = nwg >> 3, r = nwg & 7;
    const int xcd = orig & 7, idx = orig >> 3;
    const int swz = (xcd < r ? xcd * (q + 1) : r * (q + 1) + (xcd - r) * q) + idx;
    const int m0 = (swz / gx) * 128, n0 = (swz % gx) * 128;

    // staging geometry
    const int srow = tid >> 1;        // 0..127
    const int sh   = tid & 1;         // which 16-col half
    int gm = m0 + srow; if (gm > M - 1) gm = M - 1;
    int rm = gm;
    if (rev) { int b = gm / LTOK; int t = gm - b * LTOK; rm = b * LTOK + (LTOK - 1 - t); }
    const size_t aoff = (size_t)rm * lda + sh * 16;
    int gn = n0 + srow; if (gn > N - 1) gn = N - 1;
    const size_t woff = (size_t)gn * ldw + sh * 16;
    const int swz0 = ((sh * 2 + 0) ^ ((srow >> 1) & 3)) * 8;
    const int swz1 = ((sh * 2 + 1) ^ ((srow >> 1) & 3)) * 8;
    ushort_t* Awp = &Als[srow * 32];
    ushort_t* Bwp = &Bls[srow * 32];

    f32x4 acc[4][4];
#pragma unroll
    for (int i = 0; i < 4; ++i)
#pragma unroll
        for (int j = 0; j < 4; ++j) { f32x4 z = {0.f, 0.f, 0.f, 0.f}; acc[i][j] = z; }

    const int fr = lane & 15;         // frag row (A) / col (B)
    const int kg = lane >> 4;         // k-group 0..3
    const int cg = (kg ^ ((fr >> 1) & 3)) * 8;  // swizzled LDS column offset

    for (int k0 = 0; k0 < K; k0 += 32) {
        const bf16x8 a0 = *(const bf16x8*)(A + aoff + k0);
        const bf16x8 a1 = *(const bf16x8*)(A + aoff + k0 + 8);
        const bf16x8 b0 = *(const bf16x8*)(W + woff + k0);
        const bf16x8 b1 = *(const bf16x8*)(W + woff + k0 + 8);
        __syncthreads();              // prior frag reads done before overwrite
        *(bf16x8*)(Awp + swz0) = a0;
        *(bf16x8*)(Awp + swz1) = a1;
        *(bf16x8*)(Bwp + swz0) = b0;
        *(bf16x8*)(Bwp + swz1) = b1;
        __syncthreads();

        bf16x8 a4[4], b4[4];
#pragma unroll
        for (int i = 0; i < 4; ++i) {
            a4[i] = *(const bf16x8*)&Als[(wm * 64 + i * 16 + fr) * 32 + cg];
            b4[i] = *(const bf16x8*)&Bls[(wn * 64 + i * 16 + fr) * 32 + cg];
        }
#pragma unroll
        for (int mi = 0; mi < 4; ++mi)
#pragma unroll
            for (int ni = 0; ni < 4; ++ni)
                acc[mi][ni] = __builtin_amdgcn_mfma_f32_16x16x32_bf16(
                    a4[mi], b4[ni], acc[mi][ni], 0, 0, 0);
    }

    // epilogue (R4-proven): C/D layout col=lane&15, row=(lane>>4)*4+j
#pragma unroll
    for (int mi = 0; mi < 4; ++mi) {
#pragma unroll
        for (int ni = 0; ni < 4; ++ni) {
            const int gnn = n0 + wn * 64 + ni * 16 + fr;
            if (gnn >= N) continue;
#pragma unroll
            for (int j = 0; j < 4; ++j) {
                const int gmm = m0 + wm * 64 + mi * 16 + kg * 4 + j;
                if (gmm >= M) continue;
                float v = acc[mi][ni][j];
                if (bias) v += bias[gnn];
                if (act == 1) v = fmaxf(v, 0.f);
                else if (act == 2) v = (v > 20.f) ? v : log1pf(__expf(v)); // softplus
                if (res) v += res[(size_t)gmm * DM + gnn];
                if (!final_mode) {
                    out[(size_t)gmm * ldo + gnn] = v;
                } else {
                    const int bb = gmm / LTOK, vv = gmm - bb * LTOK;
                    if (vv < NVARS) {
                        out[((size_t)bb * PRED + gnn) * NVARS + vv] =
                            v * fstd[bb * NVARS + vv] + fmean[bb * NVARS + vv];
                    }
                }
            }
        }
    }
}

// ---- fp32 -> bf16 cast (grid-stride) ----
__global__ void cast_kernel(const float* __restrict__ src, ushort_t* __restrict__ dst, int n)
{
    for (int i = blockIdx.x * blockDim.x + threadIdx.x; i < n; i += gridDim.x * blockDim.x)
        dst[i] = (ushort_t)f2bf(src[i]);
}

// ---- fp32 -> bf16 weight conversion, 12 jobs in one kernel ----
struct CvtJobs {
    const float* src[12];
    ushort_t*    dst[12];
    int          n[12];
};
__global__ void cvt_kernel(CvtJobs jobs) {
    const int j = blockIdx.y;
    const float* s = jobs.src[j];
    ushort_t* d = jobs.dst[j];
    const int n = jobs.n[j];
    for (int i = blockIdx.x * blockDim.x + threadIdx.x; i < n; i += gridDim.x * blockDim.x)
        d[i] = (ushort_t)f2bf(s[i]);
}

// ---- per-(b,var) mean / stdev over SEQ ----
__global__ void stats_kernel(const float* __restrict__ x_enc,
                             float* __restrict__ means, float* __restrict__ stdev)
{
    int i = blockIdx.x * blockDim.x + threadIdx.x;
    if (i >= BATCH * NVARS) return;
    int b = i / NVARS, v = i - b * NVARS;
    const float* p = x_enc + (size_t)b * SEQ * NVARS + v;
    float s = 0.f;
    for (int t = 0; t < SEQ; ++t) s += p[(size_t)t * NVARS];
    float mu = s / (float)SEQ;
    float ss = 0.f;
    for (int t = 0; t < SEQ; ++t) { float d = p[(size_t)t * NVARS] - mu; ss += d * d; }
    means[i] = mu;
    stdev[i] = sqrtf(ss / (float)SEQ + EPS_F);
}

// ---- build token matrix (MROWS x SEQ) in bf16 ----
__global__ void tok_kernel(const float* __restrict__ x_enc, const float* __restrict__ x_mark,
                           const float* __restrict__ means, const float* __restrict__ stdev,
                           ushort_t* __restrict__ tok)
{
    int i = blockIdx.x * blockDim.x + threadIdx.x;
    if (i >= MROWS * SEQ) return;
    int s = i % SEQ;
    int row = i / SEQ;
    int b = row / LTOK, l = row - b * LTOK;
    float val;
    if (l < NVARS) {
        val = (x_enc[((size_t)b * SEQ + s) * NVARS + l] - means[b * NVARS + l])
              / stdev[b * NVARS + l];
    } else {
        val = x_mark[((size_t)b * SEQ + s) * NMARK + (l - NVARS)];
    }
    tok[i] = (ushort_t)f2bf(val);
}

// ---- causal depthwise conv (width 2) + SiLU; xz (MROWS x 1024), xi = cols [0,512) ----
__global__ void conv_silu_kernel(const float* __restrict__ xz, float* __restrict__ xc,
                                 ushort_t* __restrict__ xc_bf,
                                 const float* __restrict__ cW, const float* __restrict__ cb)
{
    int i = blockIdx.x * blockDim.x + threadIdx.x;
    if (i >= MROWS * DM) return;
    int d = i & (DM - 1);
    int row = i >> 9;
    int t = row % LTOK;
    float cur = xz[(size_t)row * 1024 + d];
    float prev = (t == 0) ? 0.f : xz[(size_t)(row - 1) * 1024 + d];
    float v = prev * cW[d * 2 + 0] + cur * cW[d * 2 + 1] + cb[d];
    float sv = v * (1.f / (1.f + __expf(-v)));   // silu
    xc[i] = sv;
    xc_bf[i] = (ushort_t)f2bf(sv);
}

// =====================================================================
// Chunked parallel selective scan (3 passes), one-lane-per-channel.
// =====================================================================
__global__ __launch_bounds__(256) void scan1_kernel(
    const float* __restrict__ xc, const float* __restrict__ dt,
    const float* __restrict__ dbc, const float* __restrict__ A_log,
    float* __restrict__ aprod, float* __restrict__ hpart)
{
    __shared__ float Ls[TCH * 32];
    const int tid = threadIdx.x;
    const int d = blockIdx.x * 256 + tid;
    const int c = blockIdx.y;
    const int b = blockIdx.z;
    const int t0 = c * TCH;
    const int tend = min(t0 + TCH, LTOK);
    const size_t rowb = (size_t)b * LTOK;

    for (int i = tid; i < TCH * 32; i += 256) {
        const int tr = min(t0 + (i >> 5), LTOK - 1);
        Ls[i] = dbc[(rowb + tr) * 64 + 32 + (i & 31)];
    }
    __syncthreads();

    float Ads[16];
#pragma unroll
    for (int s = 0; s < 16; ++s) Ads[s] = -__expf(A_log[d * DSTATE + s]);
    float h[16];
#pragma unroll
    for (int s = 0; s < 16; ++s) h[s] = 0.f;
    float sumdt = 0.f;

    for (int t = t0; t < tend; ++t) {
        const size_t row = rowb + t;
        const float dtv = dt[row * DM + d];
        const float xcv = xc[row * DM + d];
        const float du = dtv * xcv;
        sumdt += dtv;
        const float* Bp = &Ls[(t - t0) * 32];
#pragma unroll
        for (int s = 0; s < 16; ++s) {
            const float dA = __expf(dtv * Ads[s]);
            h[s] = dA * h[s] + du * Bp[s];
        }
    }
#pragma unroll
    for (int s = 0; s < 16; ++s) {
        const size_t oidx = ((size_t)(b * CCH + c) * 16 + s) * DM + d;
        aprod[oidx] = __expf(Ads[s] * sumdt);
        hpart[oidx] = h[s];
    }
}

// scan2: sequential combine over chunks; writes hinit IN-PLACE into aprod.
__global__ __launch_bounds__(256) void scan2_kernel(
    float* __restrict__ aprod, const float* __restrict__ hpart)
{
    const int gid = blockIdx.x * 256 + threadIdx.x;   // BATCH*16*DM = 131072
    const int d = gid & (DM - 1);
    const int s = (gid >> 9) & 15;
    const int b = gid >> 13;
    float h = 0.f;
    for (int c = 0; c < CCH; ++c) {
        const size_t idx = ((size_t)(b * CCH + c) * 16 + s) * DM + d;
        const float ap = aprod[idx];
        const float hp = hpart[idx];
        aprod[idx] = h;               // hinit
        h = hp + ap * h;
    }
}

__global__ __launch_bounds__(256) void scan3_kernel(
    const float* __restrict__ xc, const float* __restrict__ dt,
    const float* __restrict__ dbc, const float* __restrict__ xz,
    const float* __restrict__ A_log, const float* __restrict__ Dp,
    const float* __restrict__ hinit, ushort_t* __restrict__ ym)
{
    __shared__ float Ls[TCH * 32];
    const int tid = threadIdx.x;
    const int d = blockIdx.x * 256 + tid;
    const int c = blockIdx.y;
    const int b = blockIdx.z;
    const int t0 = c * TCH;
    const int tend = min(t0 + TCH, LTOK);
    const size_t rowb = (size_t)b * LTOK;

    for (int i = tid; i < TCH * 32; i += 256) {
        const int tr = min(t0 + (i >> 5), LTOK - 1);
        Ls[i] = dbc[(rowb + tr) * 64 + 32 + (i & 31)];
    }
    __syncthreads();

    float Ads[16];
#pragma unroll
    for (int s = 0; s < 16; ++s) Ads[s] = -__expf(A_log[d * DSTATE + s]);
    float h[16];
#pragma unroll
    for (int s = 0; s < 16; ++s)
        h[s] = hinit[((size_t)(b * CCH + c) * 16 + s) * DM + d];
    const float Dd = Dp[d];

    for (int t = t0; t < tend; ++t) {
        const size_t row = rowb + t;
        const float dtv = dt[row * DM + d];
        const float xcv = xc[row * DM + d];
        const float du = dtv * xcv;
        const float* Bp = &Ls[(t - t0) * 32];
        float p0 = 0.f, p1 = 0.f, p2 = 0.f, p3 = 0.f;
#pragma unroll
        for (int s = 0; s < 16; ++s) {
            const float dA = __expf(dtv * Ads[s]);
            const float hn = dA * h[s] + du * Bp[s];
            h[s] = hn;
            const float pc = hn * Bp[16 + s];
            if ((s & 3) == 0) p0 += pc;
            else if ((s & 3) == 1) p1 += pc;
            else if ((s & 3) == 2) p2 += pc;
            else p3 += pc;
        }
        const float y = (p0 + p1) + (p2 + p3) + xcv * Dd;
        const float z = xz[row * 1024 + DM + d];
        ym[row * DM + d] = (ushort_t)f2bf(y * (z * (1.f / (1.f + __expf(-z)))));
    }
}

// ---- LayerNorm over DM=512 per row; optional fp32 and bf16 outputs ----
__global__ __launch_bounds__(256) void ln_kernel(const float* __restrict__ in,
                                                 const float* __restrict__ w,
                                                 const float* __restrict__ bp,
                                                 float* __restrict__ outf,
                                                 ushort_t* __restrict__ outb)
{
    const int row = blockIdx.x;
    const int tid = threadIdx.x;
    const float2 v = *(const float2*)(in + (size_t)row * DM + tid * 2);
    float s  = v.x + v.y;
    float ss = v.x * v.x + v.y * v.y;
    for (int off = 32; off; off >>= 1) {
        s  += __shfl_down(s, off);
        ss += __shfl_down(ss, off);
    }
    __shared__ float sh[10];
    const int wid = tid >> 6, lane = tid & 63;
    if (lane == 0) { sh[wid] = s; sh[4 + wid] = ss; }
    __syncthreads();
    if (tid == 0) {
        float S = sh[0] + sh[1] + sh[2] + sh[3];
        float SS = sh[4] + sh[5] + sh[6] + sh[7];
        float mu = S / (float)DM;
        float var = SS / (float)DM - mu * mu;
        sh[8] = mu; sh[9] = rsqrtf(var + EPS_F);
    }
    __syncthreads();
    const float mu = sh[8], rstd = sh[9];
    const int c = tid * 2;
    float2 o;
    o.x = (v.x - mu) * rstd * w[c]     + bp[c];
    o.y = (v.y - mu) * rstd * w[c + 1] + bp[c + 1];
    if (outf) *(float2*)(outf + (size_t)row * DM + c) = o;
    if (outb) {
        unsigned pk = (unsigned)(ushort_t)f2bf(o.x) | ((unsigned)(ushort_t)f2bf(o.y) << 16);
        ((unsigned*)outb)[(size_t)row * (DM / 2) + tid] = pk;
    }
}

// =====================================================================
static inline void launch_gemm(hipStream_t st, const ushort_t* A, int lda,
                               const ushort_t* W, int ldw, const float* bias,
                               const float* res, float* out, int ldo,
                               int M, int N, int K, int rev, int act, int fin = 0,
                               const float* fstd = nullptr, const float* fmean = nullptr)
{
    const int gx = (N + 127) / 128, gy = (M + 127) / 128;
    hipLaunchKernelGGL(gemm_bf16, dim3(gx * gy), dim3(256), 0, st,
                       A, lda, W, ldw, bias, res, out, ldo,
                       M, N, K, rev, act, fin, gx, fstd, fmean);
}

extern "C" void kernel_launch(void* const* d_in, const int* in_sizes, int n_in,
                              void* d_out, int out_size, void* d_ws, size_t ws_size,
                              hipStream_t stream)
{
    const float* x_enc   = (const float*)d_in[0];
    const float* x_mark  = (const float*)d_in[1];
    const float* emb_W   = (const float*)d_in[4];
    const float* emb_b   = (const float*)d_in[5];
    const float* m_in_W[2]    = { (const float*)d_in[6],  (const float*)d_in[15] };
    const float* m_conv_W[2]  = { (const float*)d_in[7],  (const float*)d_in[16] };
    const float* m_conv_b[2]  = { (const float*)d_in[8],  (const float*)d_in[17] };
    const float* m_xproj_W[2] = { (const float*)d_in[9],  (const float*)d_in[18] };
    const float* m_dt_W[2]    = { (const float*)d_in[10], (const float*)d_in[19] };
    const float* m_dt_b[2]    = { (const float*)d_in[11], (const float*)d_in[20] };
    const float* m_A_log[2]   = { (const float*)d_in[12], (const float*)d_in[21] };
    const float* m_D[2]       = { (const float*)d_in[13], (const float*)d_in[22] };
    const float* m_out_W[2]   = { (const float*)d_in[14], (const float*)d_in[23] };
    const float* conv1_W = (const float*)d_in[24];
    const float* conv1_b = (const float*)d_in[25];
    const float* conv2_W = (const float*)d_in[26];
    const float* conv2_b = (const float*)d_in[27];
    const float* ln1_w = (const float*)d_in[28];
    const float* ln1_b = (const float*)d_in[29];
    const float* ln2_w = (const float*)d_in[30];
    const float* ln2_b = (const float*)d_in[31];
    const float* enc_w = (const float*)d_in[32];
    const float* enc_b = (const float*)d_in[33];
    const float* proj_W = (const float*)d_in[34];
    const float* proj_b = (const float*)d_in[35];

    const size_t MD = (size_t)MROWS * DM;        // 7,094,272
    float* ws = (float*)d_ws;
    size_t o = 0;
    float* means = ws + o; o += 13824;
    float* stdev = ws + o; o += 13824;
    float* xbuf  = ws + o; o += MD;              // x residual (fp32)
    float* accb  = ws + o; o += MD;              // accumulator (fp32)
    float* xzb   = ws + o; o += 2 * MD;          // xz fp32 (ldo=1024); ALIAS: x2f + hbuf
    float* xcb   = ws + o; o += MD;              // xc fp32 (scan input)
    float* dtb   = ws + o; o += MD;              // dt fp32 (scan input)
    float* dbcb  = ws + o; o += (size_t)MROWS * 64;
    float* hpart = ws + o; o += (size_t)BATCH * CCH * 16 * DM;  // 4,194,304
    float* x2f   = xzb;                          // LN1 fp32 out (xz dead at FFN)
    float* hbuf  = xzb + MD;                     // FFN hidden fp32

    ushort_t* wsb = (ushort_t*)(ws + o);
    size_t so = 0;
    ushort_t* xbuf_bf = wsb + so; so += MD;
    ushort_t* ybuf_bf = wsb + so; so += MD;      // scan out; ALIAS: ffn hidden bf16
    ushort_t* xcb_bf  = wsb + so; so += MD;      // + next buf: aprod alias region
    ushort_t* x2_bf   = wsb + so; so += MD;      // LN1/final-LN out; ALIAS: tok
    ushort_t* dbcb_bf = wsb + so; so += (size_t)MROWS * 64;
    ushort_t* embW_bf = wsb + so; so += 49152;
    ushort_t* inW_bf[2];  inW_bf[0] = wsb + so; so += 1048576; inW_bf[1] = wsb + so; so += 1048576;
    ushort_t* xpW_bf[2];  xpW_bf[0] = wsb + so; so += 65536;   xpW_bf[1] = wsb + so; so += 65536;
    ushort_t* dtW_bf[2];  dtW_bf[0] = wsb + so; so += 32768;   dtW_bf[1] = wsb + so; so += 32768;
    ushort_t* outW_bf[2]; outW_bf[0] = wsb + so; so += 524288; outW_bf[1] = wsb + so; so += 524288;
    ushort_t* c1W_bf = wsb + so; so += 524288;
    ushort_t* c2W_bf = wsb + so; so += 524288;
    ushort_t* projW_bf = wsb + so; so += 49152;
    ushort_t* tok_bf = x2_bf;                    // tok dead before LN1 writes x2
    ushort_t* hb_bf  = ybuf_bf;                  // ffn hidden bf16 after ybuf consumed
    // aprod (scan summaries, 4.19M floats) aliases [xcb_bf .. x2_bf) (7.09M floats),
    // both dead during scan1..scan3 of every layer-dir.
    float* aprod = (float*)xcb_bf;

    // 0) weight conversion (every launch; graph-safe)
    CvtJobs jobs;
    jobs.src[0] = emb_W;      jobs.dst[0] = embW_bf;    jobs.n[0] = 49152;
    jobs.src[1] = m_in_W[0];  jobs.dst[1] = inW_bf[0];  jobs.n[1] = 1048576;
    jobs.src[2] = m_in_W[1];  jobs.dst[2] = inW_bf[1];  jobs.n[2] = 1048576;
    jobs.src[3] = m_xproj_W[0]; jobs.dst[3] = xpW_bf[0]; jobs.n[3] = 65536;
    jobs.src[4] = m_xproj_W[1]; jobs.dst[4] = xpW_bf[1]; jobs.n[4] = 65536;
    jobs.src[5] = m_dt_W[0];  jobs.dst[5] = dtW_bf[0];  jobs.n[5] = 32768;
    jobs.src[6] = m_dt_W[1];  jobs.dst[6] = dtW_bf[1];  jobs.n[6] = 32768;
    jobs.src[7] = m_out_W[0]; jobs.dst[7] = outW_bf[0]; jobs.n[7] = 524288;
    jobs.src[8] = m_out_W[1]; jobs.dst[8] = outW_bf[1]; jobs.n[8] = 524288;
    jobs.src[9] = conv1_W;    jobs.dst[9] = c1W_bf;     jobs.n[9] = 524288;
    jobs.src[10] = conv2_W;   jobs.dst[10] = c2W_bf;    jobs.n[10] = 524288;
    jobs.src[11] = proj_W;    jobs.dst[11] = projW_bf;  jobs.n[11] = 49152;
    hipLaunchKernelGGL(cvt_kernel, dim3(64, 12), dim3(256), 0, stream, jobs);

    // 1) stats + token matrix + embedding (fp32 out) + cast
    hipLaunchKernelGGL(stats_kernel, dim3((BATCH * NVARS + 255) / 256), dim3(256), 0, stream,
                       x_enc, means, stdev);
    hipLaunchKernelGGL(tok_kernel, dim3((MROWS * SEQ + 255) / 256), dim3(256), 0, stream,
                       x_enc, x_mark, means, stdev, tok_bf);
    launch_gemm(stream, tok_bf, SEQ, embW_bf, SEQ, emb_b, nullptr,
                xbuf, DM, MROWS, DM, SEQ, 0, 0);
    hipLaunchKernelGGL(cast_kernel, dim3(2048), dim3(256), 0, stream,
                       xbuf, xbuf_bf, (int)MD);

    // 2) encoder layers
    for (int l = 0; l < 2; ++l) {
        for (int dir = 0; dir < 2; ++dir) {   // 0 = fwd (mf), 1 = rev (mr)
            const ushort_t* inW  = inW_bf[dir]  + (size_t)l * 2 * DM * DM;
            const float* cW   = m_conv_W[dir]  + (size_t)l * DM * 2;
            const float* cb   = m_conv_b[dir]  + (size_t)l * DM;
            const ushort_t* xpW  = xpW_bf[dir] + (size_t)l * 64 * DM;
            const ushort_t* dtW  = dtW_bf[dir] + (size_t)l * DM * DTRANK;
            const float* dtbias = m_dt_b[dir]  + (size_t)l * DM;
            const float* Alog = m_A_log[dir]   + (size_t)l * DM * DSTATE;
            const float* Dp   = m_D[dir]       + (size_t)l * DM;
            const ushort_t* outW = outW_bf[dir] + (size_t)l * DM * DM;

            // xz = x(rev?) @ in_W.T  -> xzb fp32, ldo=1024 (R4-proven store)
            launch_gemm(stream, xbuf_bf, DM, inW, DM, nullptr, nullptr,
                        xzb, 1024, MROWS, 2 * DM, DM, dir, 0);
            // xc = silu(causal_conv(xi))  (fp32 + bf16)
            hipLaunchKernelGGL(conv_silu_kernel, dim3((MROWS * DM + 255) / 256), dim3(256),
                               0, stream, xzb, xcb, xcb_bf, cW, cb);
            // dbc = xc @ xproj_W.T   (M x 64 fp32) + cast
            launch_gemm(stream, xcb_bf, DM, xpW, DM, nullptr, nullptr,
                        dbcb, 64, MROWS, 64, DM, 0, 0);
            hipLaunchKernelGGL(cast_kernel, dim3(512), dim3(256), 0, stream,
                               dbcb, dbcb_bf, MROWS * 64);
            // dt = softplus(dtr @ dt_W.T + dt_b)   (M x 512 fp32)
            launch_gemm(stream, dbcb_bf, 64, dtW, DTRANK, dtbias, nullptr,
                        dtb, DM, MROWS, DM, DTRANK, 0, 2);
            // selective scan: 3-pass chunked parallel scan (aprod aliases xcb_bf+)
            hipLaunchKernelGGL(scan1_kernel, dim3(2, CCH, BATCH), dim3(256), 0, stream,
                               xcb, dtb, dbcb, Alog, aprod, hpart);
            hipLaunchKernelGGL(scan2_kernel, dim3((BATCH * 16 * DM) / 256), dim3(256), 0, stream,
                               aprod, hpart);
            hipLaunchKernelGGL(scan3_kernel, dim3(2, CCH, BATCH), dim3(256), 0, stream,
                               xcb, dtb, dbcb, xzb, Alog, Dp, aprod, ybuf_bf);
            // acc = (dir==0 ? x : acc) + ym(rev?) @ out_W.T   (fp32 out)
            launch_gemm(stream, ybuf_bf, DM, outW, DM, nullptr,
                        dir == 0 ? xbuf : accb,
                        accb, DM, MROWS, DM, DM, dir, 0);
        }
        // x2 = LN1(acc)  (fp32 residual + bf16 A)
        hipLaunchKernelGGL(ln_kernel, dim3(MROWS), dim3(256), 0, stream,
                           accb, ln1_w + l * DM, ln1_b + l * DM, x2f, x2_bf);
        // h = relu(x2 @ conv1_W.T + b1)  (fp32 out) + cast
        launch_gemm(stream, x2_bf, DM, c1W_bf + (size_t)l * DFF * DM, DM,
                    conv1_b + l * DFF, nullptr,
                    hbuf, DFF, MROWS, DFF, DM, 0, 1);
        hipLaunchKernelGGL(cast_kernel, dim3(2048), dim3(256), 0, stream,
                           hbuf, hb_bf, (int)MD);
        // acc = x2 + h @ conv2_W.T + b2  (fp32 out)
        launch_gemm(stream, hb_bf, DFF, c2W_bf + (size_t)l * DM * DFF, DFF,
                    conv2_b + l * DM, x2f,
                    accb, DM, MROWS, DM, DFF, 0, 0);
        // x = LN2(acc)
        hipLaunchKernelGGL(ln_kernel, dim3(MROWS), dim3(256), 0, stream,
                           accb, ln2_w + l * DM, ln2_b + l * DM, xbuf, xbuf_bf);
    }

    // 3) final norm + projection + de-norm (transposed write into d_out)
    hipLaunchKernelGGL(ln_kernel, dim3(MROWS), dim3(256), 0, stream,
                       xbuf, enc_w, enc_b, nullptr, x2_bf);
    launch_gemm(stream, x2_bf, DM, projW_bf, DM, proj_b, nullptr,
                (float*)d_out, 0, MROWS, PRED, DM, 0, 0, 1, stdev, means);
}